// Round 1
// baseline (537.096 us; speedup 1.0000x reference)
//
#include <hip/hip_runtime.h>
#include <math.h>

// Problem constants (from reference)
#define NN 50000
#define EE 800000
#define EP (EE + NN)      // edges + self loops
#define CIN 128
#define HID 128
#define COUT 64
#define BB 64
#define NEG_SLOPE 0.2f
#define EPSF 1e-16f

// ---------------------------------------------------------------------------
// CSR build: count per-dst (init 1 for self-loop), scan, scatter
// ---------------------------------------------------------------------------
__global__ __launch_bounds__(256) void k_count_init(int* __restrict__ count) {
    int n = blockIdx.x * 256 + threadIdx.x;
    if (n < NN) count[n] = 1;   // self loop
}

__global__ __launch_bounds__(256) void k_count_edges(const int* __restrict__ dst,
                                                     int* __restrict__ count) {
    int e = blockIdx.x * 256 + threadIdx.x;
    if (e < EE) atomicAdd(&count[dst[e]], 1);
}

// single-block exclusive scan of count[0..NN) -> row_ptr, also copy to cursor
__global__ __launch_bounds__(1024) void k_scan(const int* __restrict__ count,
                                               int* __restrict__ row_ptr,
                                               int* __restrict__ cursor) {
    __shared__ int temp[1024];
    int tid = threadIdx.x;
    int carry = 0;
    for (int base = 0; base < NN; base += 1024) {
        int i = base + tid;
        int v = (i < NN) ? count[i] : 0;
        temp[tid] = v;
        __syncthreads();
        #pragma unroll
        for (int off = 1; off < 1024; off <<= 1) {
            int t = (tid >= off) ? temp[tid - off] : 0;
            __syncthreads();
            temp[tid] += t;
            __syncthreads();
        }
        int incl = temp[tid];
        if (i < NN) {
            int ex = carry + incl - v;
            row_ptr[i] = ex;
            cursor[i] = ex;
        }
        int tot = temp[1023];
        __syncthreads();
        carry += tot;
    }
    if (tid == 0) row_ptr[NN] = EP;
}

__global__ __launch_bounds__(256) void k_scatter(const int* __restrict__ src,
                                                 const int* __restrict__ dst,
                                                 int* __restrict__ cursor,
                                                 int* __restrict__ col_src) {
    int idx = blockIdx.x * 256 + threadIdx.x;
    if (idx >= EP) return;
    int s, d;
    if (idx < EE) { s = src[idx]; d = dst[idx]; }
    else          { s = idx - EE; d = s; }       // self loop
    int pos = atomicAdd(&cursor[d], 1);
    col_src[pos] = s;
}

// ---------------------------------------------------------------------------
// GEMM: H[N x F] = X[N x 128] @ W[128 x F]    (f32, tiled 64x64, BK=32)
// ---------------------------------------------------------------------------
template <int F>
__global__ __launch_bounds__(256) void k_gemm(const float* __restrict__ X,
                                              const float* __restrict__ W,
                                              float* __restrict__ H) {
    const int K = 128;
    __shared__ float As[64][33];
    __shared__ float Bs[32][68];
    int tid = threadIdx.x;
    int tcol = tid & 15, trow = tid >> 4;
    int row0 = blockIdx.x * 64;
    int col0 = blockIdx.y * 64;
    float acc[4][4] = {};
    for (int k0 = 0; k0 < K; k0 += 32) {
        int ar = tid >> 5, ac = tid & 31;
        #pragma unroll
        for (int i = 0; i < 8; i++) {
            int r = row0 + ar + i * 8;
            As[ar + i * 8][ac] = (r < NN) ? X[(size_t)r * K + k0 + ac] : 0.f;
        }
        int br = tid >> 6, bc = tid & 63;
        #pragma unroll
        for (int i = 0; i < 8; i++) {
            Bs[br + i * 4][bc] = W[(size_t)(k0 + br + i * 4) * F + col0 + bc];
        }
        __syncthreads();
        #pragma unroll
        for (int k = 0; k < 32; k++) {
            float a[4], b[4];
            #pragma unroll
            for (int i = 0; i < 4; i++) a[i] = As[trow * 4 + i][k];
            #pragma unroll
            for (int j = 0; j < 4; j++) b[j] = Bs[k][tcol * 4 + j];
            #pragma unroll
            for (int i = 0; i < 4; i++)
                #pragma unroll
                for (int j = 0; j < 4; j++) acc[i][j] += a[i] * b[j];
        }
        __syncthreads();
    }
    #pragma unroll
    for (int i = 0; i < 4; i++) {
        int r = row0 + trow * 4 + i;
        if (r < NN) {
            #pragma unroll
            for (int j = 0; j < 4; j++)
                H[(size_t)r * F + col0 + tcol * 4 + j] = acc[i][j];
        }
    }
}

// ---------------------------------------------------------------------------
// per-node attention scalars: s[n] = h[n].a_src, d[n] = h[n].a_dst
// one wave per node
// ---------------------------------------------------------------------------
template <int F>
__global__ __launch_bounds__(256) void k_dots(const float* __restrict__ H,
                                              const float* __restrict__ a_src,
                                              const float* __restrict__ a_dst,
                                              float* __restrict__ s,
                                              float* __restrict__ d) {
    int wave = threadIdx.x >> 6;
    int lane = threadIdx.x & 63;
    int n = blockIdx.x * 4 + wave;
    if (n >= NN) return;
    float vs, vd;
    if (F == 128) {
        float2 h = *(const float2*)&H[(size_t)n * F + lane * 2];
        float2 as = *(const float2*)&a_src[lane * 2];
        float2 ad = *(const float2*)&a_dst[lane * 2];
        vs = h.x * as.x + h.y * as.y;
        vd = h.x * ad.x + h.y * ad.y;
    } else {
        float h = H[(size_t)n * F + lane];
        vs = h * a_src[lane];
        vd = h * a_dst[lane];
    }
    #pragma unroll
    for (int off = 32; off; off >>= 1) {
        vs += __shfl_xor(vs, off);
        vd += __shfl_xor(vd, off);
    }
    if (lane == 0) { s[n] = vs; d[n] = vd; }
}

// ---------------------------------------------------------------------------
// attention softmax per destination node: att[e] over its CSR segment
// one thread per node
// ---------------------------------------------------------------------------
__global__ __launch_bounds__(256) void k_att(const int* __restrict__ row_ptr,
                                             const int* __restrict__ col_src,
                                             const float* __restrict__ s,
                                             const float* __restrict__ d,
                                             float* __restrict__ att) {
    int n = blockIdx.x * 256 + threadIdx.x;
    if (n >= NN) return;
    int beg = row_ptr[n], end = row_ptr[n + 1];
    float dn = d[n];
    float m = -3.4e38f;
    for (int e = beg; e < end; e++) {
        float l = s[col_src[e]] + dn;
        l = (l > 0.f) ? l : NEG_SLOPE * l;
        att[e] = l;
        m = fmaxf(m, l);
    }
    float sum = 0.f;
    for (int e = beg; e < end; e++) {
        float v = __expf(att[e] - m);
        att[e] = v;
        sum += v;
    }
    float inv = 1.f / (sum + EPSF);
    for (int e = beg; e < end; e++) att[e] *= inv;
}

// ---------------------------------------------------------------------------
// SpMM: out[n] = sum_e att[e] * H[col_src[e]] + bias  (opt. ReLU)
// one wave per destination node; lane = channel(s)
// ---------------------------------------------------------------------------
template <int F, bool RELU>
__global__ __launch_bounds__(256) void k_spmm(const int* __restrict__ row_ptr,
                                              const int* __restrict__ col_src,
                                              const float* __restrict__ att,
                                              const float* __restrict__ H,
                                              const float* __restrict__ bias,
                                              float* __restrict__ out) {
    int wave = threadIdx.x >> 6;
    int lane = threadIdx.x & 63;
    int n = blockIdx.x * 4 + wave;
    if (n >= NN) return;
    int beg = row_ptr[n], end = row_ptr[n + 1];
    if (F == 128) {
        float2 acc = *(const float2*)&bias[lane * 2];
        for (int e = beg; e < end; e++) {
            int src = col_src[e];
            float w = att[e];
            float2 h = *(const float2*)&H[(size_t)src * F + lane * 2];
            acc.x += w * h.x;
            acc.y += w * h.y;
        }
        if (RELU) { acc.x = fmaxf(acc.x, 0.f); acc.y = fmaxf(acc.y, 0.f); }
        *(float2*)&out[(size_t)n * F + lane * 2] = acc;
    } else {
        float acc = bias[lane];
        for (int e = beg; e < end; e++) {
            int src = col_src[e];
            float w = att[e];
            acc += w * H[(size_t)src * F + lane];
        }
        if (RELU) acc = fmaxf(acc, 0.f);
        out[(size_t)n * F + lane] = acc;
    }
}

// ---------------------------------------------------------------------------
// global mean pool (batch is SORTED) + log_softmax, one block per graph
// ---------------------------------------------------------------------------
__global__ __launch_bounds__(256) void k_pool(const float* __restrict__ out2,
                                              const int* __restrict__ batch,
                                              float* __restrict__ out) {
    __shared__ float part[4][64];
    int b = blockIdx.x;
    int tid = threadIdx.x;
    int wave = tid >> 6, lane = tid & 63;
    // lower_bound(b), lower_bound(b+1) on sorted batch
    int lo = 0, hi = NN;
    while (lo < hi) { int mid = (lo + hi) >> 1; if (batch[mid] < b) lo = mid + 1; else hi = mid; }
    int lo2 = lo, hi2 = NN;
    {
        int l = lo, h = NN;
        while (l < h) { int mid = (l + h) >> 1; if (batch[mid] < b + 1) l = mid + 1; else h = mid; }
        hi2 = h;
    }
    float acc = 0.f;
    for (int nn = lo2 + wave; nn < hi2; nn += 4) acc += out2[(size_t)nn * COUT + lane];
    part[wave][lane] = acc;
    __syncthreads();
    if (wave == 0) {
        float v = part[0][lane] + part[1][lane] + part[2][lane] + part[3][lane];
        float cnt = (float)(hi2 - lo2);
        float mean = v / fmaxf(cnt, 1.f);
        float mx = mean;
        #pragma unroll
        for (int off = 32; off; off >>= 1) mx = fmaxf(mx, __shfl_xor(mx, off));
        float ex = __expf(mean - mx);
        float sm = ex;
        #pragma unroll
        for (int off = 32; off; off >>= 1) sm += __shfl_xor(sm, off);
        out[b * COUT + lane] = mean - mx - logf(sm);
    }
}

// ---------------------------------------------------------------------------
extern "C" void kernel_launch(void* const* d_in, const int* in_sizes, int n_in,
                              void* d_out, int out_size, void* d_ws, size_t ws_size,
                              hipStream_t stream) {
    const float* x      = (const float*)d_in[0];
    const int*   eidx   = (const int*)d_in[1];
    const int*   batch  = (const int*)d_in[2];
    const float* W1     = (const float*)d_in[3];
    const float* a_src1 = (const float*)d_in[4];
    const float* a_dst1 = (const float*)d_in[5];
    const float* b1     = (const float*)d_in[6];
    const float* W2     = (const float*)d_in[7];
    const float* a_src2 = (const float*)d_in[8];
    const float* a_dst2 = (const float*)d_in[9];
    const float* b2     = (const float*)d_in[10];
    float* out = (float*)d_out;

    const int* src = eidx;        // edge_index[0]
    const int* dst = eidx + EE;   // edge_index[1]

    char* w = (char*)d_ws;
    float* h1    = (float*)w;  w += (size_t)NN * 128 * 4;
    float* x2    = (float*)w;  w += (size_t)NN * 128 * 4;
    float* h2    = (float*)w;  w += (size_t)NN * 64 * 4;
    float* out2  = (float*)w;  w += (size_t)NN * 64 * 4;
    float* s1    = (float*)w;  w += (size_t)NN * 4;
    float* d1    = (float*)w;  w += (size_t)NN * 4;
    float* att   = (float*)w;  w += (size_t)EP * 4;
    int* row_ptr = (int*)w;    w += (size_t)(NN + 1) * 4 + 4;
    int* cursor  = (int*)w;    w += (size_t)NN * 4;
    int* count   = (int*)w;    w += (size_t)NN * 4;
    int* col_src = (int*)w;    w += (size_t)EP * 4;

    dim3 blk(256);
    int gN   = (NN + 255) / 256;
    int gE   = (EE + 255) / 256;
    int gEP  = (EP + 255) / 256;
    int gN4  = (NN + 3) / 4;

    // CSR build
    k_count_init<<<gN, blk, 0, stream>>>(count);
    k_count_edges<<<gE, blk, 0, stream>>>(dst, count);
    k_scan<<<1, 1024, 0, stream>>>(count, row_ptr, cursor);
    k_scatter<<<gEP, blk, 0, stream>>>(src, dst, cursor, col_src);

    // Layer 1
    k_gemm<128><<<dim3((NN + 63) / 64, 2), blk, 0, stream>>>(x, W1, h1);
    k_dots<128><<<gN4, blk, 0, stream>>>(h1, a_src1, a_dst1, s1, d1);
    k_att<<<gN, blk, 0, stream>>>(row_ptr, col_src, s1, d1, att);
    k_spmm<128, true><<<gN4, blk, 0, stream>>>(row_ptr, col_src, att, h1, b1, x2);

    // Layer 2 (reuse s1/d1/att)
    k_gemm<64><<<dim3((NN + 63) / 64, 1), blk, 0, stream>>>(x2, W2, h2);
    k_dots<64><<<gN4, blk, 0, stream>>>(h2, a_src2, a_dst2, s1, d1);
    k_att<<<gN, blk, 0, stream>>>(row_ptr, col_src, s1, d1, att);
    k_spmm<64, false><<<gN4, blk, 0, stream>>>(row_ptr, col_src, att, h2, b2, out2);

    // Pool + log_softmax
    k_pool<<<BB, blk, 0, stream>>>(out2, batch, out);
}

// Round 2
// 366.246 us; speedup vs baseline: 1.4665x; 1.4665x over previous
//
#include <hip/hip_runtime.h>
#include <math.h>

// Problem constants (from reference)
#define NN 50000
#define EE 800000
#define EP (EE + NN)      // edges + self loops
#define COUT 64
#define BB 64
#define NEG_SLOPE 0.2f
#define EPSF 1e-16f

typedef unsigned short u16;

// ---- bf16 helpers (round-to-nearest-even encode) ---------------------------
__device__ __forceinline__ u16 f2b(float f) {
    union { float f; unsigned u; } v; v.f = f;
    unsigned u = v.u;
    return (u16)((u + 0x7FFFu + ((u >> 16) & 1u)) >> 16);
}
__device__ __forceinline__ float b2f(u16 h) {
    union { unsigned u; float f; } v; v.u = ((unsigned)h) << 16;
    return v.f;
}

// ---------------------------------------------------------------------------
// CSR build: count per-dst (init 1 for self-loop), scan, scatter
// ---------------------------------------------------------------------------
__global__ __launch_bounds__(256) void k_count_init(int* __restrict__ count) {
    int n = blockIdx.x * 256 + threadIdx.x;
    if (n < NN) count[n] = 1;   // self loop
}

__global__ __launch_bounds__(256) void k_count_edges(const int* __restrict__ dst,
                                                     int* __restrict__ count) {
    int e = blockIdx.x * 256 + threadIdx.x;
    if (e < EE) atomicAdd(&count[dst[e]], 1);
}

// single-block exclusive scan (wave-shfl based, 3 barriers per 1024 chunk)
__global__ __launch_bounds__(1024) void k_scan(const int* __restrict__ count,
                                               int* __restrict__ row_ptr,
                                               int* __restrict__ cursor) {
    __shared__ int wsum[16];
    __shared__ int wincl[16];
    int tid = threadIdx.x;
    int wv = tid >> 6, ln = tid & 63;
    int carry = 0;
    for (int base = 0; base < NN; base += 1024) {
        int i = base + tid;
        int v = (i < NN) ? count[i] : 0;
        int x = v;
        #pragma unroll
        for (int off = 1; off < 64; off <<= 1) {
            int t = __shfl_up(x, off);
            if (ln >= off) x += t;
        }
        if (ln == 63) wsum[wv] = x;
        __syncthreads();
        if (tid < 16) {
            int y = wsum[tid];
            #pragma unroll
            for (int off = 1; off < 16; off <<= 1) {
                int t = __shfl_up(y, off);
                if (tid >= off) y += t;
            }
            wincl[tid] = y;
        }
        __syncthreads();
        int ex = carry + (wv ? wincl[wv - 1] : 0) + x - v;
        if (i < NN) { row_ptr[i] = ex; cursor[i] = ex; }
        carry += wincl[15];
        __syncthreads();
    }
    if (tid == 0) row_ptr[NN] = EP;
}

__global__ __launch_bounds__(256) void k_scatter(const int* __restrict__ src,
                                                 const int* __restrict__ dst,
                                                 int* __restrict__ cursor,
                                                 int* __restrict__ col_src) {
    int idx = blockIdx.x * 256 + threadIdx.x;
    if (idx >= EP) return;
    int s, d;
    if (idx < EE) { s = src[idx]; d = dst[idx]; }
    else          { s = idx - EE; d = s; }       // self loop
    int pos = atomicAdd(&cursor[d], 1);
    col_src[pos] = s;
}

// ---------------------------------------------------------------------------
// GEMM: H[N x F](bf16) = X[N x 128] @ W[128 x F]   (f32 math, tiled 64x64)
// A is f32 (layer 1) or bf16 (layer 2)
// ---------------------------------------------------------------------------
template <int F, bool ABF16>
__global__ __launch_bounds__(256) void k_gemm(const void* __restrict__ Xv,
                                              const float* __restrict__ W,
                                              u16* __restrict__ H) {
    const int K = 128;
    __shared__ float As[64][33];
    __shared__ float Bs[32][68];
    int tid = threadIdx.x;
    int tcol = tid & 15, trow = tid >> 4;
    int row0 = blockIdx.x * 64;
    int col0 = blockIdx.y * 64;
    float acc[4][4] = {};
    for (int k0 = 0; k0 < K; k0 += 32) {
        if (ABF16) {
            const u16* X = (const u16*)Xv;
            int ar = tid >> 4;          // 0..15
            int ac = (tid & 15) * 2;    // 0..30
            #pragma unroll
            for (int i = 0; i < 4; i++) {
                int r = row0 + ar + i * 16;
                ushort2 t;
                if (r < NN) t = *(const ushort2*)&X[(size_t)r * K + k0 + ac];
                else        { t.x = 0; t.y = 0; }
                As[ar + i * 16][ac]     = b2f(t.x);
                As[ar + i * 16][ac + 1] = b2f(t.y);
            }
        } else {
            const float* X = (const float*)Xv;
            int ar = tid >> 5, ac = tid & 31;
            #pragma unroll
            for (int i = 0; i < 8; i++) {
                int r = row0 + ar + i * 8;
                As[ar + i * 8][ac] = (r < NN) ? X[(size_t)r * K + k0 + ac] : 0.f;
            }
        }
        int br = tid >> 6, bc = tid & 63;
        #pragma unroll
        for (int i = 0; i < 8; i++) {
            Bs[br + i * 4][bc] = W[(size_t)(k0 + br + i * 4) * F + col0 + bc];
        }
        __syncthreads();
        #pragma unroll
        for (int k = 0; k < 32; k++) {
            float a[4], b[4];
            #pragma unroll
            for (int i = 0; i < 4; i++) a[i] = As[trow * 4 + i][k];
            #pragma unroll
            for (int j = 0; j < 4; j++) b[j] = Bs[k][tcol * 4 + j];
            #pragma unroll
            for (int i = 0; i < 4; i++)
                #pragma unroll
                for (int j = 0; j < 4; j++) acc[i][j] += a[i] * b[j];
        }
        __syncthreads();
    }
    #pragma unroll
    for (int i = 0; i < 4; i++) {
        int r = row0 + trow * 4 + i;
        if (r < NN) {
            ushort4 o;
            o.x = f2b(acc[i][0]); o.y = f2b(acc[i][1]);
            o.z = f2b(acc[i][2]); o.w = f2b(acc[i][3]);
            *(ushort4*)&H[(size_t)r * F + col0 + tcol * 4] = o;
        }
    }
}

// ---------------------------------------------------------------------------
// per-node attention scalars: s[n] = h[n].a_src, d[n] = h[n].a_dst  (bf16 H)
// ---------------------------------------------------------------------------
template <int F>
__global__ __launch_bounds__(256) void k_dots(const u16* __restrict__ H,
                                              const float* __restrict__ a_src,
                                              const float* __restrict__ a_dst,
                                              float* __restrict__ s,
                                              float* __restrict__ d) {
    int wave = threadIdx.x >> 6;
    int lane = threadIdx.x & 63;
    int n = blockIdx.x * 4 + wave;
    if (n >= NN) return;
    float vs, vd;
    if (F == 128) {
        ushort2 t = *(const ushort2*)&H[(size_t)n * F + lane * 2];
        float h0 = b2f(t.x), h1 = b2f(t.y);
        float2 as = *(const float2*)&a_src[lane * 2];
        float2 ad = *(const float2*)&a_dst[lane * 2];
        vs = h0 * as.x + h1 * as.y;
        vd = h0 * ad.x + h1 * ad.y;
    } else {
        float h = b2f(H[(size_t)n * F + lane]);
        vs = h * a_src[lane];
        vd = h * a_dst[lane];
    }
    #pragma unroll
    for (int off = 32; off; off >>= 1) {
        vs += __shfl_xor(vs, off);
        vd += __shfl_xor(vd, off);
    }
    if (lane == 0) { s[n] = vs; d[n] = vd; }
}

// ---------------------------------------------------------------------------
// Fused attention-softmax + SpMM.  One wave per destination node.
// Pass A: lane-parallel online softmax stats (M, S) over the node's edges.
// Pass B: serial edge loop (4x unrolled), lane = channel(s); att weight is
//         recomputed per edge (cheap VALU) -> no att buffer at all.
// ---------------------------------------------------------------------------
__device__ __forceinline__ float leaky(float v) {
    return (v > 0.f) ? v : NEG_SLOPE * v;
}

template <int F, bool RELU, bool OUTB>
__global__ __launch_bounds__(256) void k_fused(const int* __restrict__ row_ptr,
                                               const int* __restrict__ col_src,
                                               const float* __restrict__ s,
                                               const float* __restrict__ d,
                                               const u16* __restrict__ H,
                                               const float* __restrict__ bias,
                                               void* __restrict__ outv) {
    int wave = threadIdx.x >> 6;
    int lane = threadIdx.x & 63;
    int n = blockIdx.x * 4 + wave;
    if (n >= NN) return;
    int beg = row_ptr[n], end = row_ptr[n + 1];
    float dn = d[n];

    // ---- pass A: online softmax stats over edges (lane-parallel) ----
    float M = -INFINITY, S = 0.f;
    for (int e0 = beg; e0 < end; e0 += 64) {
        int e = e0 + lane;
        float l = -INFINITY;
        if (e < end) l = leaky(s[col_src[e]] + dn);
        float cm = l;
        #pragma unroll
        for (int off = 32; off; off >>= 1) cm = fmaxf(cm, __shfl_xor(cm, off));
        float Mn = fmaxf(M, cm);
        float p = (e < end) ? __expf(l - Mn) : 0.f;
        #pragma unroll
        for (int off = 32; off; off >>= 1) p += __shfl_xor(p, off);
        S = S * __expf(M - Mn) + p;
        M = Mn;
    }
    float invS = 1.f / (S + EPSF);

    // ---- pass B: gather-accumulate ----
    if (F == 128) {
        float2 acc = *(const float2*)&bias[lane * 2];
        int e = beg;
        for (; e + 4 <= end; e += 4) {
            int c0 = col_src[e + 0], c1 = col_src[e + 1];
            int c2 = col_src[e + 2], c3 = col_src[e + 3];
            float sv0 = s[c0], sv1 = s[c1], sv2 = s[c2], sv3 = s[c3];
            ushort2 r0 = *(const ushort2*)&H[(size_t)c0 * F + lane * 2];
            ushort2 r1 = *(const ushort2*)&H[(size_t)c1 * F + lane * 2];
            ushort2 r2 = *(const ushort2*)&H[(size_t)c2 * F + lane * 2];
            ushort2 r3 = *(const ushort2*)&H[(size_t)c3 * F + lane * 2];
            float w0 = __expf(leaky(sv0 + dn) - M) * invS;
            float w1 = __expf(leaky(sv1 + dn) - M) * invS;
            float w2 = __expf(leaky(sv2 + dn) - M) * invS;
            float w3 = __expf(leaky(sv3 + dn) - M) * invS;
            acc.x += w0 * b2f(r0.x); acc.y += w0 * b2f(r0.y);
            acc.x += w1 * b2f(r1.x); acc.y += w1 * b2f(r1.y);
            acc.x += w2 * b2f(r2.x); acc.y += w2 * b2f(r2.y);
            acc.x += w3 * b2f(r3.x); acc.y += w3 * b2f(r3.y);
        }
        for (; e < end; ++e) {
            int c = col_src[e];
            float w = __expf(leaky(s[c] + dn) - M) * invS;
            ushort2 r = *(const ushort2*)&H[(size_t)c * F + lane * 2];
            acc.x += w * b2f(r.x); acc.y += w * b2f(r.y);
        }
        if (RELU) { acc.x = fmaxf(acc.x, 0.f); acc.y = fmaxf(acc.y, 0.f); }
        if (OUTB) {
            ushort2 o; o.x = f2b(acc.x); o.y = f2b(acc.y);
            *(ushort2*)&((u16*)outv)[(size_t)n * F + lane * 2] = o;
        } else {
            *(float2*)&((float*)outv)[(size_t)n * F + lane * 2] = acc;
        }
    } else {  // F == 64
        float acc = bias[lane];
        int e = beg;
        for (; e + 4 <= end; e += 4) {
            int c0 = col_src[e + 0], c1 = col_src[e + 1];
            int c2 = col_src[e + 2], c3 = col_src[e + 3];
            float sv0 = s[c0], sv1 = s[c1], sv2 = s[c2], sv3 = s[c3];
            u16 r0 = H[(size_t)c0 * F + lane];
            u16 r1 = H[(size_t)c1 * F + lane];
            u16 r2 = H[(size_t)c2 * F + lane];
            u16 r3 = H[(size_t)c3 * F + lane];
            float w0 = __expf(leaky(sv0 + dn) - M) * invS;
            float w1 = __expf(leaky(sv1 + dn) - M) * invS;
            float w2 = __expf(leaky(sv2 + dn) - M) * invS;
            float w3 = __expf(leaky(sv3 + dn) - M) * invS;
            acc += w0 * b2f(r0) + w1 * b2f(r1) + w2 * b2f(r2) + w3 * b2f(r3);
        }
        for (; e < end; ++e) {
            int c = col_src[e];
            float w = __expf(leaky(s[c] + dn) - M) * invS;
            acc += w * b2f(H[(size_t)c * F + lane]);
        }
        if (RELU) acc = fmaxf(acc, 0.f);
        if (OUTB) ((u16*)outv)[(size_t)n * F + lane] = f2b(acc);
        else      ((float*)outv)[(size_t)n * F + lane] = acc;
    }
}

// ---------------------------------------------------------------------------
// global mean pool (batch is SORTED) + log_softmax, one block per graph
// ---------------------------------------------------------------------------
__global__ __launch_bounds__(256) void k_pool(const float* __restrict__ out2,
                                              const int* __restrict__ batch,
                                              float* __restrict__ out) {
    __shared__ float part[4][64];
    int b = blockIdx.x;
    int tid = threadIdx.x;
    int wave = tid >> 6, lane = tid & 63;
    int lo = 0, hi = NN;
    while (lo < hi) { int mid = (lo + hi) >> 1; if (batch[mid] < b) lo = mid + 1; else hi = mid; }
    int lo2 = lo, hi2;
    {
        int l = lo, h = NN;
        while (l < h) { int mid = (l + h) >> 1; if (batch[mid] < b + 1) l = mid + 1; else h = mid; }
        hi2 = h;
    }
    float acc = 0.f;
    for (int nn = lo2 + wave; nn < hi2; nn += 4) acc += out2[(size_t)nn * COUT + lane];
    part[wave][lane] = acc;
    __syncthreads();
    if (wave == 0) {
        float v = part[0][lane] + part[1][lane] + part[2][lane] + part[3][lane];
        float cnt = (float)(hi2 - lo2);
        float mean = v / fmaxf(cnt, 1.f);
        float mx = mean;
        #pragma unroll
        for (int off = 32; off; off >>= 1) mx = fmaxf(mx, __shfl_xor(mx, off));
        float ex = __expf(mean - mx);
        float sm = ex;
        #pragma unroll
        for (int off = 32; off; off >>= 1) sm += __shfl_xor(sm, off);
        out[b * COUT + lane] = mean - mx - logf(sm);
    }
}

// ---------------------------------------------------------------------------
extern "C" void kernel_launch(void* const* d_in, const int* in_sizes, int n_in,
                              void* d_out, int out_size, void* d_ws, size_t ws_size,
                              hipStream_t stream) {
    const float* x      = (const float*)d_in[0];
    const int*   eidx   = (const int*)d_in[1];
    const int*   batch  = (const int*)d_in[2];
    const float* W1     = (const float*)d_in[3];
    const float* a_src1 = (const float*)d_in[4];
    const float* a_dst1 = (const float*)d_in[5];
    const float* b1     = (const float*)d_in[6];
    const float* W2     = (const float*)d_in[7];
    const float* a_src2 = (const float*)d_in[8];
    const float* a_dst2 = (const float*)d_in[9];
    const float* b2     = (const float*)d_in[10];
    float* out = (float*)d_out;

    const int* src = eidx;        // edge_index[0]
    const int* dst = eidx + EE;   // edge_index[1]

    char* w = (char*)d_ws;
    auto alloc = [&](size_t bytes) { void* p = (void*)w; w += (bytes + 255) & ~(size_t)255; return p; };
    float* out2  = (float*)alloc((size_t)NN * 64 * 4);
    float* s1    = (float*)alloc((size_t)NN * 4);
    float* d1    = (float*)alloc((size_t)NN * 4);
    int* row_ptr = (int*)alloc((size_t)(NN + 1) * 4);
    int* cursor  = (int*)alloc((size_t)NN * 4);
    int* count   = (int*)alloc((size_t)NN * 4);
    int* col_src = (int*)alloc((size_t)EP * 4);
    u16* h1      = (u16*)alloc((size_t)NN * 128 * 2);
    u16* x2      = (u16*)alloc((size_t)NN * 128 * 2);
    u16* h2      = (u16*)alloc((size_t)NN * 64 * 2);

    dim3 blk(256);
    int gN   = (NN + 255) / 256;
    int gE   = (EE + 255) / 256;
    int gEP  = (EP + 255) / 256;
    int gN4  = (NN + 3) / 4;

    // CSR build
    k_count_init<<<gN, blk, 0, stream>>>(count);
    k_count_edges<<<gE, blk, 0, stream>>>(dst, count);
    k_scan<<<1, 1024, 0, stream>>>(count, row_ptr, cursor);
    k_scatter<<<gEP, blk, 0, stream>>>(src, dst, cursor, col_src);

    // Layer 1
    k_gemm<128, false><<<dim3((NN + 63) / 64, 2), blk, 0, stream>>>(x, W1, h1);
    k_dots<128><<<gN4, blk, 0, stream>>>(h1, a_src1, a_dst1, s1, d1);
    k_fused<128, true, true><<<gN4, blk, 0, stream>>>(row_ptr, col_src, s1, d1, h1, b1, x2);

    // Layer 2
    k_gemm<64, true><<<dim3((NN + 63) / 64, 1), blk, 0, stream>>>(x2, W2, h2);
    k_dots<64><<<gN4, blk, 0, stream>>>(h2, a_src2, a_dst2, s1, d1);
    k_fused<64, false, false><<<gN4, blk, 0, stream>>>(row_ptr, col_src, s1, d1, h2, b2, out2);

    // Pool + log_softmax
    k_pool<<<BB, blk, 0, stream>>>(out2, batch, out);
}

// Round 3
// 295.424 us; speedup vs baseline: 1.8181x; 1.2397x over previous
//
#include <hip/hip_runtime.h>
#include <math.h>

// Problem constants (from reference)
#define NN 50000
#define EE 800000
#define EP (EE + NN)      // edges + self loops
#define COUT 64
#define BB 64
#define NEG_SLOPE 0.2f
#define EPSF 1e-16f
#define NPART 8
#define PNODES (NN / NPART)   // 6250, exact

typedef unsigned short u16;

// ---- bf16 helpers (round-to-nearest-even encode) ---------------------------
__device__ __forceinline__ u16 f2b(float f) {
    union { float f; unsigned u; } v; v.f = f;
    unsigned u = v.u;
    return (u16)((u + 0x7FFFu + ((u >> 16) & 1u)) >> 16);
}
__device__ __forceinline__ float b2f(u16 h) {
    union { unsigned u; float f; } v; v.u = ((unsigned)h) << 16;
    return v.f;
}
__device__ __forceinline__ float leaky(float v) {
    return (v > 0.f) ? v : NEG_SLOPE * v;
}

// ---------------------------------------------------------------------------
// init: count=1 (self loop), zero s1/d1 and pooled sums
// ---------------------------------------------------------------------------
__global__ __launch_bounds__(256) void k_init(int* __restrict__ count,
                                              float* __restrict__ s1,
                                              float* __restrict__ d1,
                                              float* __restrict__ sums) {
    int n = blockIdx.x * 256 + threadIdx.x;
    if (n < NN) { count[n] = 1; s1[n] = 0.f; d1[n] = 0.f; }
    if (n < BB * COUT) sums[n] = 0.f;
}

__global__ __launch_bounds__(256) void k_count_edges(const int* __restrict__ dst,
                                                     int* __restrict__ count) {
    int e = blockIdx.x * 256 + threadIdx.x;
    if (e < EE) atomicAdd(&count[dst[e]], 1);
}

// single-block exclusive scan (wave-shfl based)
__global__ __launch_bounds__(1024) void k_scan(const int* __restrict__ count,
                                               int* __restrict__ row_ptr,
                                               int* __restrict__ cursor) {
    __shared__ int wsum[16];
    __shared__ int wincl[16];
    int tid = threadIdx.x;
    int wv = tid >> 6, ln = tid & 63;
    int carry = 0;
    for (int base = 0; base < NN; base += 1024) {
        int i = base + tid;
        int v = (i < NN) ? count[i] : 0;
        int x = v;
        #pragma unroll
        for (int off = 1; off < 64; off <<= 1) {
            int t = __shfl_up(x, off);
            if (ln >= off) x += t;
        }
        if (ln == 63) wsum[wv] = x;
        __syncthreads();
        if (tid < 16) {
            int y = wsum[tid];
            #pragma unroll
            for (int off = 1; off < 16; off <<= 1) {
                int t = __shfl_up(y, off);
                if (tid >= off) y += t;
            }
            wincl[tid] = y;
        }
        __syncthreads();
        int ex = carry + (wv ? wincl[wv - 1] : 0) + x - v;
        if (i < NN) { row_ptr[i] = ex; cursor[i] = ex; }
        carry += wincl[15];
        __syncthreads();
    }
    if (tid == 0) row_ptr[NN] = EP;
}

// ---------------------------------------------------------------------------
// Partitioned scatter: block owns dst-partition v = blockIdx.x & 7.
// All blocks with the same v deterministically partition the edge list, so
// every edge is committed exactly once regardless of block->XCD placement.
// With %8 round-robin placement, each col_src line is dirtied by one XCD only.
// ---------------------------------------------------------------------------
__global__ __launch_bounds__(256) void k_scatter(const int* __restrict__ src,
                                                 const int* __restrict__ dst,
                                                 int* __restrict__ cursor,
                                                 int* __restrict__ col_src) {
    int v = blockIdx.x & (NPART - 1);
    int cid = blockIdx.x >> 3;
    int nchunk = gridDim.x >> 3;
    int lo = v * PNODES, hi = lo + PNODES;
    for (int e = cid * 256 + threadIdx.x; e < EP; e += nchunk * 256) {
        int s, dd;
        if (e < EE) { s = src[e]; dd = dst[e]; }
        else        { s = e - EE; dd = s; }
        if (dd >= lo && dd < hi) {
            int pos = atomicAdd(&cursor[dd], 1);
            col_src[pos] = s;
        }
    }
}

// ---------------------------------------------------------------------------
// GEMM: H[N x F](bf16) = X[N x 128] @ W[128 x F]   (f32 math, tiled 64x64)
// Epilogue also computes per-row partial dots with a_src/a_dst -> s[], d[]
// (atomicAdd when gridDim.y > 1, else direct store).
// ---------------------------------------------------------------------------
template <int F, bool ABF16, bool DOT_ATOMIC>
__global__ __launch_bounds__(256) void k_gemm(const void* __restrict__ Xv,
                                              const float* __restrict__ W,
                                              u16* __restrict__ H,
                                              const float* __restrict__ a_src,
                                              const float* __restrict__ a_dst,
                                              float* __restrict__ sdot,
                                              float* __restrict__ ddot) {
    const int K = 128;
    __shared__ float As[64][33];
    __shared__ float Bs[32][68];
    int tid = threadIdx.x;
    int tcol = tid & 15, trow = tid >> 4;
    int row0 = blockIdx.x * 64;
    int col0 = blockIdx.y * 64;
    float acc[4][4] = {};
    for (int k0 = 0; k0 < K; k0 += 32) {
        if (ABF16) {
            const u16* X = (const u16*)Xv;
            int ar = tid >> 4;
            int ac = (tid & 15) * 2;
            #pragma unroll
            for (int i = 0; i < 4; i++) {
                int r = row0 + ar + i * 16;
                ushort2 t;
                if (r < NN) t = *(const ushort2*)&X[(size_t)r * K + k0 + ac];
                else        { t.x = 0; t.y = 0; }
                As[ar + i * 16][ac]     = b2f(t.x);
                As[ar + i * 16][ac + 1] = b2f(t.y);
            }
        } else {
            const float* X = (const float*)Xv;
            int ar = tid >> 5, ac = tid & 31;
            #pragma unroll
            for (int i = 0; i < 8; i++) {
                int r = row0 + ar + i * 8;
                As[ar + i * 8][ac] = (r < NN) ? X[(size_t)r * K + k0 + ac] : 0.f;
            }
        }
        int br = tid >> 6, bc = tid & 63;
        #pragma unroll
        for (int i = 0; i < 8; i++) {
            Bs[br + i * 4][bc] = W[(size_t)(k0 + br + i * 4) * F + col0 + bc];
        }
        __syncthreads();
        #pragma unroll
        for (int k = 0; k < 32; k++) {
            float a[4], b[4];
            #pragma unroll
            for (int i = 0; i < 4; i++) a[i] = As[trow * 4 + i][k];
            #pragma unroll
            for (int j = 0; j < 4; j++) b[j] = Bs[k][tcol * 4 + j];
            #pragma unroll
            for (int i = 0; i < 4; i++)
                #pragma unroll
                for (int j = 0; j < 4; j++) acc[i][j] += a[i] * b[j];
        }
        __syncthreads();
    }
    // C write (bf16)
    #pragma unroll
    for (int i = 0; i < 4; i++) {
        int r = row0 + trow * 4 + i;
        if (r < NN) {
            ushort4 o;
            o.x = f2b(acc[i][0]); o.y = f2b(acc[i][1]);
            o.z = f2b(acc[i][2]); o.w = f2b(acc[i][3]);
            *(ushort4*)&H[(size_t)r * F + col0 + tcol * 4] = o;
        }
    }
    // fused attention dots: per-row partials over this 64-col tile
    float as[4], ad[4];
    #pragma unroll
    for (int j = 0; j < 4; j++) {
        as[j] = a_src[col0 + tcol * 4 + j];
        ad[j] = a_dst[col0 + tcol * 4 + j];
    }
    #pragma unroll
    for (int i = 0; i < 4; i++) {
        float ps = acc[i][0] * as[0] + acc[i][1] * as[1] + acc[i][2] * as[2] + acc[i][3] * as[3];
        float pd = acc[i][0] * ad[0] + acc[i][1] * ad[1] + acc[i][2] * ad[2] + acc[i][3] * ad[3];
        #pragma unroll
        for (int off = 1; off < 16; off <<= 1) {
            ps += __shfl_xor(ps, off);
            pd += __shfl_xor(pd, off);
        }
        int r = row0 + trow * 4 + i;
        if (tcol == 0 && r < NN) {
            if (DOT_ATOMIC) { atomicAdd(&sdot[r], ps); atomicAdd(&ddot[r], pd); }
            else            { sdot[r] = ps; ddot[r] = pd; }
        }
    }
}

// ---------------------------------------------------------------------------
// Fused attention-softmax + SpMM, layer 1 (F=128, ReLU, bf16 out).
// One wave per destination node.
// ---------------------------------------------------------------------------
__global__ __launch_bounds__(256) void k_fused1(const int* __restrict__ row_ptr,
                                                const int* __restrict__ col_src,
                                                const float* __restrict__ s,
                                                const float* __restrict__ d,
                                                const u16* __restrict__ H,
                                                const float* __restrict__ bias,
                                                u16* __restrict__ outb) {
    const int F = 128;
    int wave = threadIdx.x >> 6;
    int lane = threadIdx.x & 63;
    int n = blockIdx.x * 4 + wave;
    if (n >= NN) return;
    int beg = row_ptr[n], end = row_ptr[n + 1];
    float dn = d[n];

    float M = -INFINITY, S = 0.f;
    for (int e0 = beg; e0 < end; e0 += 64) {
        int e = e0 + lane;
        float l = -INFINITY;
        if (e < end) l = leaky(s[col_src[e]] + dn);
        float cm = l;
        #pragma unroll
        for (int off = 32; off; off >>= 1) cm = fmaxf(cm, __shfl_xor(cm, off));
        float Mn = fmaxf(M, cm);
        float p = (e < end) ? __expf(l - Mn) : 0.f;
        #pragma unroll
        for (int off = 32; off; off >>= 1) p += __shfl_xor(p, off);
        S = S * __expf(M - Mn) + p;
        M = Mn;
    }
    float invS = 1.f / (S + EPSF);

    float2 acc = *(const float2*)&bias[lane * 2];
    int e = beg;
    for (; e + 4 <= end; e += 4) {
        int c0 = col_src[e + 0], c1 = col_src[e + 1];
        int c2 = col_src[e + 2], c3 = col_src[e + 3];
        float sv0 = s[c0], sv1 = s[c1], sv2 = s[c2], sv3 = s[c3];
        ushort2 r0 = *(const ushort2*)&H[(size_t)c0 * F + lane * 2];
        ushort2 r1 = *(const ushort2*)&H[(size_t)c1 * F + lane * 2];
        ushort2 r2 = *(const ushort2*)&H[(size_t)c2 * F + lane * 2];
        ushort2 r3 = *(const ushort2*)&H[(size_t)c3 * F + lane * 2];
        float w0 = __expf(leaky(sv0 + dn) - M) * invS;
        float w1 = __expf(leaky(sv1 + dn) - M) * invS;
        float w2 = __expf(leaky(sv2 + dn) - M) * invS;
        float w3 = __expf(leaky(sv3 + dn) - M) * invS;
        acc.x += w0 * b2f(r0.x); acc.y += w0 * b2f(r0.y);
        acc.x += w1 * b2f(r1.x); acc.y += w1 * b2f(r1.y);
        acc.x += w2 * b2f(r2.x); acc.y += w2 * b2f(r2.y);
        acc.x += w3 * b2f(r3.x); acc.y += w3 * b2f(r3.y);
    }
    for (; e < end; ++e) {
        int c = col_src[e];
        float w = __expf(leaky(s[c] + dn) - M) * invS;
        ushort2 r = *(const ushort2*)&H[(size_t)c * F + lane * 2];
        acc.x += w * b2f(r.x); acc.y += w * b2f(r.y);
    }
    acc.x = fmaxf(acc.x, 0.f); acc.y = fmaxf(acc.y, 0.f);
    ushort2 o; o.x = f2b(acc.x); o.y = f2b(acc.y);
    *(ushort2*)&outb[(size_t)n * F + lane * 2] = o;
}

// ---------------------------------------------------------------------------
// Fused attention-softmax + SpMM + global-mean-pool accumulate, layer 2
// (F=64, no ReLU). One wave handles NPW consecutive nodes; per-graph row sums
// accumulate in registers (batch is sorted) and flush via atomicAdd.
// ---------------------------------------------------------------------------
#define NPW 8
__global__ __launch_bounds__(256) void k_fused2(const int* __restrict__ row_ptr,
                                                const int* __restrict__ col_src,
                                                const float* __restrict__ s,
                                                const float* __restrict__ d,
                                                const u16* __restrict__ H,
                                                const float* __restrict__ bias,
                                                const int* __restrict__ batch,
                                                float* __restrict__ sums) {
    const int F = 64;
    int wave = threadIdx.x >> 6;
    int lane = threadIdx.x & 63;
    int base = (blockIdx.x * 4 + wave) * NPW;
    if (base >= NN) return;
    int lim = base + NPW; if (lim > NN) lim = NN;
    float bs = bias[lane];
    float gacc = 0.f;
    int gb = batch[base];

    for (int n = base; n < lim; ++n) {
        int b = batch[n];
        if (b != gb) {
            atomicAdd(&sums[gb * COUT + lane], gacc);
            gacc = 0.f; gb = b;
        }
        int beg = row_ptr[n], end = row_ptr[n + 1];
        float dn = d[n];

        float M = -INFINITY, S = 0.f;
        for (int e0 = beg; e0 < end; e0 += 64) {
            int e = e0 + lane;
            float l = -INFINITY;
            if (e < end) l = leaky(s[col_src[e]] + dn);
            float cm = l;
            #pragma unroll
            for (int off = 32; off; off >>= 1) cm = fmaxf(cm, __shfl_xor(cm, off));
            float Mn = fmaxf(M, cm);
            float p = (e < end) ? __expf(l - Mn) : 0.f;
            #pragma unroll
            for (int off = 32; off; off >>= 1) p += __shfl_xor(p, off);
            S = S * __expf(M - Mn) + p;
            M = Mn;
        }
        float invS = 1.f / (S + EPSF);

        float acc = bs;
        int e = beg;
        for (; e + 4 <= end; e += 4) {
            int c0 = col_src[e + 0], c1 = col_src[e + 1];
            int c2 = col_src[e + 2], c3 = col_src[e + 3];
            float sv0 = s[c0], sv1 = s[c1], sv2 = s[c2], sv3 = s[c3];
            u16 r0 = H[(size_t)c0 * F + lane];
            u16 r1 = H[(size_t)c1 * F + lane];
            u16 r2 = H[(size_t)c2 * F + lane];
            u16 r3 = H[(size_t)c3 * F + lane];
            float w0 = __expf(leaky(sv0 + dn) - M) * invS;
            float w1 = __expf(leaky(sv1 + dn) - M) * invS;
            float w2 = __expf(leaky(sv2 + dn) - M) * invS;
            float w3 = __expf(leaky(sv3 + dn) - M) * invS;
            acc += w0 * b2f(r0) + w1 * b2f(r1) + w2 * b2f(r2) + w3 * b2f(r3);
        }
        for (; e < end; ++e) {
            int c = col_src[e];
            float w = __expf(leaky(s[c] + dn) - M) * invS;
            acc += w * b2f(H[(size_t)c * F + lane]);
        }
        gacc += acc;
    }
    atomicAdd(&sums[gb * COUT + lane], gacc);
}

// ---------------------------------------------------------------------------
// mean + log_softmax; one wave per graph; counts via bsearch on sorted batch
// ---------------------------------------------------------------------------
__global__ __launch_bounds__(256) void k_logsm(const float* __restrict__ sums,
                                               const int* __restrict__ batch,
                                               float* __restrict__ out) {
    int wave = threadIdx.x >> 6;
    int lane = threadIdx.x & 63;
    int g = blockIdx.x * 4 + wave;
    if (g >= BB) return;
    int lo = 0, hi = NN;
    while (lo < hi) { int mid = (lo + hi) >> 1; if (batch[mid] < g) lo = mid + 1; else hi = mid; }
    int l2 = lo, h2 = NN;
    while (l2 < h2) { int mid = (l2 + h2) >> 1; if (batch[mid] < g + 1) l2 = mid + 1; else h2 = mid; }
    float cnt = (float)(h2 - lo);
    float mean = sums[g * COUT + lane] / fmaxf(cnt, 1.f);
    float mx = mean;
    #pragma unroll
    for (int off = 32; off; off >>= 1) mx = fmaxf(mx, __shfl_xor(mx, off));
    float ex = __expf(mean - mx);
    float sm = ex;
    #pragma unroll
    for (int off = 32; off; off >>= 1) sm += __shfl_xor(sm, off);
    out[g * COUT + lane] = mean - mx - logf(sm);
}

// ---------------------------------------------------------------------------
extern "C" void kernel_launch(void* const* d_in, const int* in_sizes, int n_in,
                              void* d_out, int out_size, void* d_ws, size_t ws_size,
                              hipStream_t stream) {
    const float* x      = (const float*)d_in[0];
    const int*   eidx   = (const int*)d_in[1];
    const int*   batch  = (const int*)d_in[2];
    const float* W1     = (const float*)d_in[3];
    const float* a_src1 = (const float*)d_in[4];
    const float* a_dst1 = (const float*)d_in[5];
    const float* b1     = (const float*)d_in[6];
    const float* W2     = (const float*)d_in[7];
    const float* a_src2 = (const float*)d_in[8];
    const float* a_dst2 = (const float*)d_in[9];
    const float* b2     = (const float*)d_in[10];
    float* out = (float*)d_out;

    const int* src = eidx;        // edge_index[0]
    const int* dst = eidx + EE;   // edge_index[1]

    char* w = (char*)d_ws;
    auto alloc = [&](size_t bytes) { void* p = (void*)w; w += (bytes + 255) & ~(size_t)255; return p; };
    float* sums  = (float*)alloc((size_t)BB * COUT * 4);
    float* s1    = (float*)alloc((size_t)NN * 4);
    float* d1    = (float*)alloc((size_t)NN * 4);
    float* s2    = (float*)alloc((size_t)NN * 4);
    float* d2    = (float*)alloc((size_t)NN * 4);
    int* row_ptr = (int*)alloc((size_t)(NN + 1) * 4);
    int* cursor  = (int*)alloc((size_t)NN * 4);
    int* count   = (int*)alloc((size_t)NN * 4);
    int* col_src = (int*)alloc((size_t)EP * 4);
    u16* h1      = (u16*)alloc((size_t)NN * 128 * 2);
    u16* x2      = (u16*)alloc((size_t)NN * 128 * 2);
    u16* h2      = (u16*)alloc((size_t)NN * 64 * 2);

    dim3 blk(256);
    int gN  = (NN + 255) / 256;
    int gE  = (EE + 255) / 256;
    int gN4 = (NN + 3) / 4;

    // CSR build
    k_init<<<gN, blk, 0, stream>>>(count, s1, d1, sums);
    k_count_edges<<<gE, blk, 0, stream>>>(dst, count);
    k_scan<<<1, 1024, 0, stream>>>(count, row_ptr, cursor);
    k_scatter<<<2048, blk, 0, stream>>>(src, dst, cursor, col_src);

    // Layer 1: GEMM(+dots), fused softmax/SpMM
    k_gemm<128, false, true><<<dim3((NN + 63) / 64, 2), blk, 0, stream>>>(
        x, W1, h1, a_src1, a_dst1, s1, d1);
    k_fused1<<<gN4, blk, 0, stream>>>(row_ptr, col_src, s1, d1, h1, b1, x2);

    // Layer 2: GEMM(+dots, direct store), fused softmax/SpMM/pool
    k_gemm<64, true, false><<<dim3((NN + 63) / 64, 1), blk, 0, stream>>>(
        x2, W2, h2, a_src2, a_dst2, s2, d2);
    int gP = (NN + 4 * NPW - 1) / (4 * NPW);
    k_fused2<<<gP, blk, 0, stream>>>(row_ptr, col_src, s2, d2, h2, b2, batch, sums);

    // mean + log_softmax
    k_logsm<<<(BB + 3) / 4, blk, 0, stream>>>(sums, batch, out);
}

// Round 4
// 270.337 us; speedup vs baseline: 1.9868x; 1.0928x over previous
//
#include <hip/hip_runtime.h>
#include <math.h>

// Problem constants (from reference)
#define NN 50000
#define EE 800000
#define EP (EE + NN)      // edges + self loops
#define COUT 64
#define BB 64
#define NEG_SLOPE 0.2f
#define EPSF 1e-16f
#define NPART 8
#define PNODES (NN / NPART)   // 6250, exact
#define CAP 128               // LDS-staged max degree (fallback above)

typedef unsigned short u16;

// ---- bf16 helpers (round-to-nearest-even encode) ---------------------------
__device__ __forceinline__ u16 f2b(float f) {
    union { float f; unsigned u; } v; v.f = f;
    unsigned u = v.u;
    return (u16)((u + 0x7FFFu + ((u >> 16) & 1u)) >> 16);
}
__device__ __forceinline__ float b2f(u16 h) {
    union { unsigned u; float f; } v; v.u = ((unsigned)h) << 16;
    return v.f;
}
__device__ __forceinline__ float leaky(float v) {
    return (v > 0.f) ? v : NEG_SLOPE * v;
}

// ---------------------------------------------------------------------------
// init: count=1 (self loop), zero s1/d1 and pooled sums
// ---------------------------------------------------------------------------
__global__ __launch_bounds__(256) void k_init(int* __restrict__ count,
                                              float* __restrict__ s1,
                                              float* __restrict__ d1,
                                              float* __restrict__ sums) {
    int n = blockIdx.x * 256 + threadIdx.x;
    if (n < NN) { count[n] = 1; s1[n] = 0.f; d1[n] = 0.f; }
    if (n < BB * COUT) sums[n] = 0.f;
}

__global__ __launch_bounds__(256) void k_count_edges(const int* __restrict__ dst,
                                                     int* __restrict__ count) {
    int e = blockIdx.x * 256 + threadIdx.x;
    if (e < EE) atomicAdd(&count[dst[e]], 1);
}

// single-block exclusive scan (wave-shfl based)
__global__ __launch_bounds__(1024) void k_scan(const int* __restrict__ count,
                                               int* __restrict__ row_ptr,
                                               int* __restrict__ cursor) {
    __shared__ int wsum[16];
    __shared__ int wincl[16];
    int tid = threadIdx.x;
    int wv = tid >> 6, ln = tid & 63;
    int carry = 0;
    for (int base = 0; base < NN; base += 1024) {
        int i = base + tid;
        int v = (i < NN) ? count[i] : 0;
        int x = v;
        #pragma unroll
        for (int off = 1; off < 64; off <<= 1) {
            int t = __shfl_up(x, off);
            if (ln >= off) x += t;
        }
        if (ln == 63) wsum[wv] = x;
        __syncthreads();
        if (tid < 16) {
            int y = wsum[tid];
            #pragma unroll
            for (int off = 1; off < 16; off <<= 1) {
                int t = __shfl_up(y, off);
                if (tid >= off) y += t;
            }
            wincl[tid] = y;
        }
        __syncthreads();
        int ex = carry + (wv ? wincl[wv - 1] : 0) + x - v;
        if (i < NN) { row_ptr[i] = ex; cursor[i] = ex; }
        carry += wincl[15];
        __syncthreads();
    }
    if (tid == 0) row_ptr[NN] = EP;
}

// ---------------------------------------------------------------------------
// Partitioned scatter (one dst-partition per blockIdx%8 -> per-XCD lines)
// ---------------------------------------------------------------------------
__global__ __launch_bounds__(256) void k_scatter(const int* __restrict__ src,
                                                 const int* __restrict__ dst,
                                                 int* __restrict__ cursor,
                                                 int* __restrict__ col_src) {
    int v = blockIdx.x & (NPART - 1);
    int cid = blockIdx.x >> 3;
    int nchunk = gridDim.x >> 3;
    int lo = v * PNODES, hi = lo + PNODES;
    for (int e = cid * 256 + threadIdx.x; e < EP; e += nchunk * 256) {
        int s, dd;
        if (e < EE) { s = src[e]; dd = dst[e]; }
        else        { s = e - EE; dd = s; }
        if (dd >= lo && dd < hi) {
            int pos = atomicAdd(&cursor[dd], 1);
            col_src[pos] = s;
        }
    }
}

// ---------------------------------------------------------------------------
// GEMM with fused attention-dot epilogue (f32 math, tiled 64x64)
// ---------------------------------------------------------------------------
template <int F, bool ABF16, bool DOT_ATOMIC>
__global__ __launch_bounds__(256) void k_gemm(const void* __restrict__ Xv,
                                              const float* __restrict__ W,
                                              u16* __restrict__ H,
                                              const float* __restrict__ a_src,
                                              const float* __restrict__ a_dst,
                                              float* __restrict__ sdot,
                                              float* __restrict__ ddot) {
    const int K = 128;
    __shared__ float As[64][33];
    __shared__ float Bs[32][68];
    int tid = threadIdx.x;
    int tcol = tid & 15, trow = tid >> 4;
    int row0 = blockIdx.x * 64;
    int col0 = blockIdx.y * 64;
    float acc[4][4] = {};
    for (int k0 = 0; k0 < K; k0 += 32) {
        if (ABF16) {
            const u16* X = (const u16*)Xv;
            int ar = tid >> 4;
            int ac = (tid & 15) * 2;
            #pragma unroll
            for (int i = 0; i < 4; i++) {
                int r = row0 + ar + i * 16;
                ushort2 t;
                if (r < NN) t = *(const ushort2*)&X[(size_t)r * K + k0 + ac];
                else        { t.x = 0; t.y = 0; }
                As[ar + i * 16][ac]     = b2f(t.x);
                As[ar + i * 16][ac + 1] = b2f(t.y);
            }
        } else {
            const float* X = (const float*)Xv;
            int ar = tid >> 5, ac = tid & 31;
            #pragma unroll
            for (int i = 0; i < 8; i++) {
                int r = row0 + ar + i * 8;
                As[ar + i * 8][ac] = (r < NN) ? X[(size_t)r * K + k0 + ac] : 0.f;
            }
        }
        int br = tid >> 6, bc = tid & 63;
        #pragma unroll
        for (int i = 0; i < 8; i++) {
            Bs[br + i * 4][bc] = W[(size_t)(k0 + br + i * 4) * F + col0 + bc];
        }
        __syncthreads();
        #pragma unroll
        for (int k = 0; k < 32; k++) {
            float a[4], b[4];
            #pragma unroll
            for (int i = 0; i < 4; i++) a[i] = As[trow * 4 + i][k];
            #pragma unroll
            for (int j = 0; j < 4; j++) b[j] = Bs[k][tcol * 4 + j];
            #pragma unroll
            for (int i = 0; i < 4; i++)
                #pragma unroll
                for (int j = 0; j < 4; j++) acc[i][j] += a[i] * b[j];
        }
        __syncthreads();
    }
    #pragma unroll
    for (int i = 0; i < 4; i++) {
        int r = row0 + trow * 4 + i;
        if (r < NN) {
            ushort4 o;
            o.x = f2b(acc[i][0]); o.y = f2b(acc[i][1]);
            o.z = f2b(acc[i][2]); o.w = f2b(acc[i][3]);
            *(ushort4*)&H[(size_t)r * F + col0 + tcol * 4] = o;
        }
    }
    float as[4], ad[4];
    #pragma unroll
    for (int j = 0; j < 4; j++) {
        as[j] = a_src[col0 + tcol * 4 + j];
        ad[j] = a_dst[col0 + tcol * 4 + j];
    }
    #pragma unroll
    for (int i = 0; i < 4; i++) {
        float ps = acc[i][0] * as[0] + acc[i][1] * as[1] + acc[i][2] * as[2] + acc[i][3] * as[3];
        float pd = acc[i][0] * ad[0] + acc[i][1] * ad[1] + acc[i][2] * ad[2] + acc[i][3] * ad[3];
        #pragma unroll
        for (int off = 1; off < 16; off <<= 1) {
            ps += __shfl_xor(ps, off);
            pd += __shfl_xor(pd, off);
        }
        int r = row0 + trow * 4 + i;
        if (tcol == 0 && r < NN) {
            if (DOT_ATOMIC) { atomicAdd(&sdot[r], ps); atomicAdd(&ddot[r], pd); }
            else            { sdot[r] = ps; ddot[r] = pd; }
        }
    }
}

// ---------------------------------------------------------------------------
// Shared helper: lane-parallel softmax weights into LDS.
// Returns invS; LDS wl[0..degR) holds u_e = exp(l_e - M); wc holds col idx.
// Requires deg <= CAP. degR = ceil(deg/64)*64 (pad u = 0).
// ---------------------------------------------------------------------------
__device__ __forceinline__ float stage_weights(const int* __restrict__ col_src,
                                               const float* __restrict__ s,
                                               float dn, int beg, int end, int lane,
                                               float* __restrict__ wl,
                                               int* __restrict__ wc) {
    float M = -INFINITY;
    for (int e0 = beg; e0 < end; e0 += 64) {
        int e = e0 + lane;
        float l = -INFINITY; int c = 0;
        if (e < end) { c = col_src[e]; l = leaky(s[c] + dn); }
        wl[e0 - beg + lane] = l;
        wc[e0 - beg + lane] = c;
        float cm = l;
        #pragma unroll
        for (int off = 32; off; off >>= 1) cm = fmaxf(cm, __shfl_xor(cm, off));
        M = fmaxf(M, cm);
    }
    float Sl = 0.f;
    for (int i0 = 0; i0 < end - beg; i0 += 64) {
        float u = __expf(wl[i0 + lane] - M);   // exp(-inf)=0 for pad
        wl[i0 + lane] = u;
        Sl += u;
    }
    #pragma unroll
    for (int off = 32; off; off >>= 1) Sl += __shfl_xor(Sl, off);
    return 1.f / (Sl + EPSF);
}

// ---------------------------------------------------------------------------
// Fused softmax+SpMM, layer 1 (F=128, ReLU, bf16 out). One wave per node.
// ---------------------------------------------------------------------------
__global__ __launch_bounds__(256) void k_fused1(const int* __restrict__ row_ptr,
                                                const int* __restrict__ col_src,
                                                const float* __restrict__ s,
                                                const float* __restrict__ d,
                                                const u16* __restrict__ H,
                                                const float* __restrict__ bias,
                                                u16* __restrict__ outb) {
    const int F = 128;
    __shared__ float wl[4][CAP];
    __shared__ int   wc[4][CAP];
    int wave = threadIdx.x >> 6;
    int lane = threadIdx.x & 63;
    int n = blockIdx.x * 4 + wave;
    if (n >= NN) return;
    int beg = row_ptr[n], end = row_ptr[n + 1];
    int deg = end - beg;
    float dn = d[n];
    float2 acc = {0.f, 0.f};
    float invS;

    if (deg <= CAP) {
        invS = stage_weights(col_src, s, dn, beg, end, lane, wl[wave], wc[wave]);
        int i = 0;
        for (; i + 4 <= deg; i += 4) {
            float u0 = wl[wave][i], u1 = wl[wave][i + 1];
            float u2 = wl[wave][i + 2], u3 = wl[wave][i + 3];
            int c0 = wc[wave][i], c1 = wc[wave][i + 1];
            int c2 = wc[wave][i + 2], c3 = wc[wave][i + 3];
            ushort2 r0 = *(const ushort2*)&H[(size_t)c0 * F + lane * 2];
            ushort2 r1 = *(const ushort2*)&H[(size_t)c1 * F + lane * 2];
            ushort2 r2 = *(const ushort2*)&H[(size_t)c2 * F + lane * 2];
            ushort2 r3 = *(const ushort2*)&H[(size_t)c3 * F + lane * 2];
            acc.x += u0 * b2f(r0.x); acc.y += u0 * b2f(r0.y);
            acc.x += u1 * b2f(r1.x); acc.y += u1 * b2f(r1.y);
            acc.x += u2 * b2f(r2.x); acc.y += u2 * b2f(r2.y);
            acc.x += u3 * b2f(r3.x); acc.y += u3 * b2f(r3.y);
        }
        for (; i < deg; ++i) {
            float u = wl[wave][i];
            int c = wc[wave][i];
            ushort2 r = *(const ushort2*)&H[(size_t)c * F + lane * 2];
            acc.x += u * b2f(r.x); acc.y += u * b2f(r.y);
        }
    } else {  // fallback: online softmax + recompute (statistically unreachable)
        float M = -INFINITY, S = 0.f;
        for (int e0 = beg; e0 < end; e0 += 64) {
            int e = e0 + lane;
            float l = (e < end) ? leaky(s[col_src[e]] + dn) : -INFINITY;
            float cm = l;
            #pragma unroll
            for (int off = 32; off; off >>= 1) cm = fmaxf(cm, __shfl_xor(cm, off));
            float Mn = fmaxf(M, cm);
            float p = (e < end) ? __expf(l - Mn) : 0.f;
            #pragma unroll
            for (int off = 32; off; off >>= 1) p += __shfl_xor(p, off);
            S = S * __expf(M - Mn) + p;
            M = Mn;
        }
        invS = 1.f / (S + EPSF);
        for (int e = beg; e < end; ++e) {
            int c = col_src[e];
            float u = __expf(leaky(s[c] + dn) - M);
            ushort2 r = *(const ushort2*)&H[(size_t)c * F + lane * 2];
            acc.x += u * b2f(r.x); acc.y += u * b2f(r.y);
        }
        float2 b = *(const float2*)&bias[lane * 2];
        acc.x = fmaxf(acc.x * invS + b.x, 0.f);
        acc.y = fmaxf(acc.y * invS + b.y, 0.f);
        ushort2 o; o.x = f2b(acc.x); o.y = f2b(acc.y);
        *(ushort2*)&outb[(size_t)n * F + lane * 2] = o;
        return;
    }
    float2 b = *(const float2*)&bias[lane * 2];
    acc.x = fmaxf(acc.x * invS + b.x, 0.f);
    acc.y = fmaxf(acc.y * invS + b.y, 0.f);
    ushort2 o; o.x = f2b(acc.x); o.y = f2b(acc.y);
    *(ushort2*)&outb[(size_t)n * F + lane * 2] = o;
}

// ---------------------------------------------------------------------------
// Fused softmax+SpMM+mean-pool accumulate, layer 2 (F=64).
// One wave handles NPW consecutive nodes (batch sorted); flush via atomicAdd.
// ---------------------------------------------------------------------------
#define NPW 8
__global__ __launch_bounds__(256) void k_fused2(const int* __restrict__ row_ptr,
                                                const int* __restrict__ col_src,
                                                const float* __restrict__ s,
                                                const float* __restrict__ d,
                                                const u16* __restrict__ H,
                                                const float* __restrict__ bias,
                                                const int* __restrict__ batch,
                                                float* __restrict__ sums) {
    const int F = 64;
    __shared__ float wl[4][CAP];
    __shared__ int   wc[4][CAP];
    int wave = threadIdx.x >> 6;
    int lane = threadIdx.x & 63;
    int base = (blockIdx.x * 4 + wave) * NPW;
    if (base >= NN) return;
    int lim = base + NPW; if (lim > NN) lim = NN;
    float bs = bias[lane];
    float gacc = 0.f;
    int gb = batch[base];

    for (int n = base; n < lim; ++n) {
        int b = batch[n];
        if (b != gb) {
            atomicAdd(&sums[gb * COUT + lane], gacc);
            gacc = 0.f; gb = b;
        }
        int beg = row_ptr[n], end = row_ptr[n + 1];
        int deg = end - beg;
        float dn = d[n];
        float acc = 0.f;
        float invS;

        if (deg <= CAP) {
            invS = stage_weights(col_src, s, dn, beg, end, lane, wl[wave], wc[wave]);
            int i = 0;
            for (; i + 4 <= deg; i += 4) {
                float u0 = wl[wave][i], u1 = wl[wave][i + 1];
                float u2 = wl[wave][i + 2], u3 = wl[wave][i + 3];
                int c0 = wc[wave][i], c1 = wc[wave][i + 1];
                int c2 = wc[wave][i + 2], c3 = wc[wave][i + 3];
                u16 r0 = H[(size_t)c0 * F + lane];
                u16 r1 = H[(size_t)c1 * F + lane];
                u16 r2 = H[(size_t)c2 * F + lane];
                u16 r3 = H[(size_t)c3 * F + lane];
                acc += u0 * b2f(r0) + u1 * b2f(r1) + u2 * b2f(r2) + u3 * b2f(r3);
            }
            for (; i < deg; ++i) {
                acc += wl[wave][i] * b2f(H[(size_t)wc[wave][i] * F + lane]);
            }
        } else {  // fallback
            float M = -INFINITY, S = 0.f;
            for (int e0 = beg; e0 < end; e0 += 64) {
                int e = e0 + lane;
                float l = (e < end) ? leaky(s[col_src[e]] + dn) : -INFINITY;
                float cm = l;
                #pragma unroll
                for (int off = 32; off; off >>= 1) cm = fmaxf(cm, __shfl_xor(cm, off));
                float Mn = fmaxf(M, cm);
                float p = (e < end) ? __expf(l - Mn) : 0.f;
                #pragma unroll
                for (int off = 32; off; off >>= 1) p += __shfl_xor(p, off);
                S = S * __expf(M - Mn) + p;
                M = Mn;
            }
            invS = 1.f / (S + EPSF);
            for (int e = beg; e < end; ++e) {
                int c = col_src[e];
                acc += __expf(leaky(s[c] + dn) - M) * b2f(H[(size_t)c * F + lane]);
            }
        }
        gacc += acc * invS + bs;
    }
    atomicAdd(&sums[gb * COUT + lane], gacc);
}

// ---------------------------------------------------------------------------
// mean + log_softmax; one wave per graph
// ---------------------------------------------------------------------------
__global__ __launch_bounds__(256) void k_logsm(const float* __restrict__ sums,
                                               const int* __restrict__ batch,
                                               float* __restrict__ out) {
    int wave = threadIdx.x >> 6;
    int lane = threadIdx.x & 63;
    int g = blockIdx.x * 4 + wave;
    if (g >= BB) return;
    int lo = 0, hi = NN;
    while (lo < hi) { int mid = (lo + hi) >> 1; if (batch[mid] < g) lo = mid + 1; else hi = mid; }
    int l2 = lo, h2 = NN;
    while (l2 < h2) { int mid = (l2 + h2) >> 1; if (batch[mid] < g + 1) l2 = mid + 1; else h2 = mid; }
    float cnt = (float)(h2 - lo);
    float mean = sums[g * COUT + lane] / fmaxf(cnt, 1.f);
    float mx = mean;
    #pragma unroll
    for (int off = 32; off; off >>= 1) mx = fmaxf(mx, __shfl_xor(mx, off));
    float ex = __expf(mean - mx);
    float sm = ex;
    #pragma unroll
    for (int off = 32; off; off >>= 1) sm += __shfl_xor(sm, off);
    out[g * COUT + lane] = mean - mx - logf(sm);
}

// ---------------------------------------------------------------------------
extern "C" void kernel_launch(void* const* d_in, const int* in_sizes, int n_in,
                              void* d_out, int out_size, void* d_ws, size_t ws_size,
                              hipStream_t stream) {
    const float* x      = (const float*)d_in[0];
    const int*   eidx   = (const int*)d_in[1];
    const int*   batch  = (const int*)d_in[2];
    const float* W1     = (const float*)d_in[3];
    const float* a_src1 = (const float*)d_in[4];
    const float* a_dst1 = (const float*)d_in[5];
    const float* b1     = (const float*)d_in[6];
    const float* W2     = (const float*)d_in[7];
    const float* a_src2 = (const float*)d_in[8];
    const float* a_dst2 = (const float*)d_in[9];
    const float* b2     = (const float*)d_in[10];
    float* out = (float*)d_out;

    const int* src = eidx;        // edge_index[0]
    const int* dst = eidx + EE;   // edge_index[1]

    char* w = (char*)d_ws;
    auto alloc = [&](size_t bytes) { void* p = (void*)w; w += (bytes + 255) & ~(size_t)255; return p; };
    float* sums  = (float*)alloc((size_t)BB * COUT * 4);
    float* s1    = (float*)alloc((size_t)NN * 4);
    float* d1    = (float*)alloc((size_t)NN * 4);
    float* s2    = (float*)alloc((size_t)NN * 4);
    float* d2    = (float*)alloc((size_t)NN * 4);
    int* row_ptr = (int*)alloc((size_t)(NN + 1) * 4);
    int* cursor  = (int*)alloc((size_t)NN * 4);
    int* count   = (int*)alloc((size_t)NN * 4);
    int* col_src = (int*)alloc((size_t)EP * 4);
    u16* h1      = (u16*)alloc((size_t)NN * 128 * 2);
    u16* x2      = (u16*)alloc((size_t)NN * 128 * 2);
    u16* h2      = (u16*)alloc((size_t)NN * 64 * 2);

    dim3 blk(256);
    int gN  = (NN + 255) / 256;
    int gE  = (EE + 255) / 256;
    int gN4 = (NN + 3) / 4;

    // CSR build
    k_init<<<gN, blk, 0, stream>>>(count, s1, d1, sums);
    k_count_edges<<<gE, blk, 0, stream>>>(dst, count);
    k_scan<<<1, 1024, 0, stream>>>(count, row_ptr, cursor);
    k_scatter<<<2048, blk, 0, stream>>>(src, dst, cursor, col_src);

    // Layer 1
    k_gemm<128, false, true><<<dim3((NN + 63) / 64, 2), blk, 0, stream>>>(
        x, W1, h1, a_src1, a_dst1, s1, d1);
    k_fused1<<<gN4, blk, 0, stream>>>(row_ptr, col_src, s1, d1, h1, b1, x2);

    // Layer 2
    k_gemm<64, true, false><<<dim3((NN + 63) / 64, 1), blk, 0, stream>>>(
        x2, W2, h2, a_src2, a_dst2, s2, d2);
    int gP = (NN + 4 * NPW - 1) / (4 * NPW);
    k_fused2<<<gP, blk, 0, stream>>>(row_ptr, col_src, s2, d2, h2, b2, batch, sums);

    // mean + log_softmax
    k_logsm<<<(BB + 3) / 4, blk, 0, stream>>>(sums, batch, out);
}

// Round 5
// 194.848 us; speedup vs baseline: 2.7565x; 1.3874x over previous
//
#include <hip/hip_runtime.h>
#include <math.h>

// Problem constants (from reference)
#define NN 50000
#define EE 800000
#define EP (EE + NN)      // edges + self loops
#define COUT 64
#define BB 64
#define NEG_SLOPE 0.2f
#define EPSF 1e-16f
#define NPART 8
#define PNODES (NN / NPART)   // 6250, exact
#define CAP 128               // LDS-staged max degree (fallback above)

typedef unsigned short u16;
typedef __attribute__((ext_vector_type(8))) short bf16x8;
typedef __attribute__((ext_vector_type(4))) float f32x4;

// ---- bf16 helpers (round-to-nearest-even encode) ---------------------------
__device__ __forceinline__ u16 f2b(float f) {
    union { float f; unsigned u; } v; v.f = f;
    unsigned u = v.u;
    return (u16)((u + 0x7FFFu + ((u >> 16) & 1u)) >> 16);
}
__device__ __forceinline__ float b2f(u16 h) {
    union { unsigned u; float f; } v; v.u = ((unsigned)h) << 16;
    return v.f;
}
__device__ __forceinline__ float leaky(float v) {
    return (v > 0.f) ? v : NEG_SLOPE * v;
}

// ---------------------------------------------------------------------------
// init: count=1 (self loop), zero pooled sums
// ---------------------------------------------------------------------------
__global__ __launch_bounds__(256) void k_init(int* __restrict__ count,
                                              float* __restrict__ sums) {
    int n = blockIdx.x * 256 + threadIdx.x;
    if (n < NN) count[n] = 1;
    if (n < BB * COUT) sums[n] = 0.f;
}

__global__ __launch_bounds__(256) void k_count_edges(const int* __restrict__ dst,
                                                     int* __restrict__ count) {
    int e = blockIdx.x * 256 + threadIdx.x;
    if (e < EE) atomicAdd(&count[dst[e]], 1);
}

// ---------------------------------------------------------------------------
// W transpose + bf16 convert: W1t[c][k] = W1[k][c], W2t[c][k] = W2[k][c]
// ---------------------------------------------------------------------------
__global__ __launch_bounds__(256) void k_prep(const float* __restrict__ W1,
                                              const float* __restrict__ W2,
                                              u16* __restrict__ W1t,
                                              u16* __restrict__ W2t) {
    int t = blockIdx.x * 256 + threadIdx.x;
    if (t < 128 * 128) {
        int c = t >> 7, k = t & 127;
        W1t[t] = f2b(W1[k * 128 + c]);
    } else {
        int o = t - 128 * 128;
        if (o < 64 * 128) {
            int c = o >> 7, k = o & 127;
            W2t[o] = f2b(W2[k * 64 + c]);
        }
    }
}

// ---------------------------------------------------------------------------
// Multi-block scan: (1) per-block exclusive scan + block total
//                   (2) add prefix of block totals (<=49 blocks, wave reduce)
// ---------------------------------------------------------------------------
__global__ __launch_bounds__(1024) void k_scan1(const int* __restrict__ count,
                                                int* __restrict__ tmp,
                                                int* __restrict__ partial) {
    __shared__ int wsum[16];
    __shared__ int wincl[16];
    int tid = threadIdx.x;
    int wv = tid >> 6, ln = tid & 63;
    int i = blockIdx.x * 1024 + tid;
    int v = (i < NN) ? count[i] : 0;
    int x = v;
    #pragma unroll
    for (int off = 1; off < 64; off <<= 1) {
        int t = __shfl_up(x, off);
        if (ln >= off) x += t;
    }
    if (ln == 63) wsum[wv] = x;
    __syncthreads();
    if (tid < 16) {
        int y = wsum[tid];
        #pragma unroll
        for (int off = 1; off < 16; off <<= 1) {
            int t = __shfl_up(y, off);
            if (tid >= off) y += t;
        }
        wincl[tid] = y;
    }
    __syncthreads();
    int ex = (wv ? wincl[wv - 1] : 0) + x - v;
    if (i < NN) tmp[i] = ex;
    if (tid == 0) partial[blockIdx.x] = wincl[15];
}

__global__ __launch_bounds__(1024) void k_scan2(const int* __restrict__ tmp,
                                                const int* __restrict__ partial,
                                                int* __restrict__ row_ptr,
                                                int* __restrict__ cursor) {
    __shared__ int off_s;
    int b = blockIdx.x;
    int tid = threadIdx.x;
    if (tid < 64) {
        int p = (tid < b) ? partial[tid] : 0;   // b <= 48 < 64
        #pragma unroll
        for (int off = 32; off; off >>= 1) p += __shfl_xor(p, off);
        if (tid == 0) off_s = p;
    }
    __syncthreads();
    int i = b * 1024 + tid;
    if (i < NN) {
        int r = tmp[i] + off_s;
        row_ptr[i] = r;
        cursor[i] = r;
    }
    if (b == 0 && tid == 0) row_ptr[NN] = EP;
}

// ---------------------------------------------------------------------------
// Partitioned scatter (one dst-partition per blockIdx%8 -> per-XCD lines)
// ---------------------------------------------------------------------------
__global__ __launch_bounds__(256) void k_scatter(const int* __restrict__ src,
                                                 const int* __restrict__ dst,
                                                 int* __restrict__ cursor,
                                                 int* __restrict__ col_src) {
    int v = blockIdx.x & (NPART - 1);
    int cid = blockIdx.x >> 3;
    int nchunk = gridDim.x >> 3;
    int lo = v * PNODES, hi = lo + PNODES;
    for (int e = cid * 256 + threadIdx.x; e < EP; e += nchunk * 256) {
        int s, dd;
        if (e < EE) { s = src[e]; dd = dst[e]; }
        else        { s = e - EE; dd = s; }
        if (dd >= lo && dd < hi) {
            int pos = atomicAdd(&cursor[dd], 1);
            col_src[pos] = s;
        }
    }
}

// ---------------------------------------------------------------------------
// MFMA bf16 GEMM: H[N x F](bf16) = X[N x 128] @ W[128 x F]
// Block: 64 rows x full N; whole K=128 in LDS; XOR-swizzled LDS (u16 units:
// idx ^= (row&7)<<3) for conflict-free b128 fragment reads.
// Fragments (mfma_f32_16x16x32_bf16): A row=lane&15, k=(lane>>4)*8+j;
// B col=lane&15, same k; D col=lane&15, row=(lane>>4)*4+reg.
// Epilogue: bf16 H store + fused a_src/a_dst dots (direct store, no atomics).
// ---------------------------------------------------------------------------
template <int F, bool ABF16>
__global__ __launch_bounds__(256) void k_gemm_mfma(const void* __restrict__ Xv,
                                                   const u16* __restrict__ Wt,
                                                   u16* __restrict__ H,
                                                   const float* __restrict__ a_src,
                                                   const float* __restrict__ a_dst,
                                                   float* __restrict__ sdot,
                                                   float* __restrict__ ddot) {
    __shared__ u16 Ab[64 * 128];
    __shared__ u16 Bb[F * 128];
    int tid = threadIdx.x;
    int row0 = blockIdx.x * 64;

    // ---- stage A (64 x 128, bf16, swizzled) ----
    if (ABF16) {
        const u16* X = (const u16*)Xv;
        #pragma unroll
        for (int it = 0; it < 4; it++) {
            int c = it * 256 + tid;        // 8-u16 chunk id (1024 total)
            int row = c >> 4;
            int k8 = (c & 15) * 8;
            int grow = row0 + row;
            uint4 val = {0u, 0u, 0u, 0u};
            if (grow < NN) val = *(const uint4*)&X[(size_t)grow * 128 + k8];
            *(uint4*)&Ab[row * 128 + (k8 ^ ((row & 7) << 3))] = val;
        }
    } else {
        const float* X = (const float*)Xv;
        #pragma unroll
        for (int it = 0; it < 8; it++) {
            int c = it * 256 + tid;        // float4 id (2048 total)
            int e = c * 4;
            int row = e >> 7;
            int col = e & 127;
            int grow = row0 + row;
            float4 v = {0.f, 0.f, 0.f, 0.f};
            if (grow < NN) v = *(const float4*)&X[(size_t)grow * 128 + col];
            ushort4 o;
            o.x = f2b(v.x); o.y = f2b(v.y); o.z = f2b(v.z); o.w = f2b(v.w);
            *(ushort4*)&Ab[row * 128 + (col ^ ((row & 7) << 3))] = o;
        }
    }
    // ---- stage B (F x 128 = Wt, bf16, swizzled) ----
    const int NB = F * 128 / 8 / 256;
    #pragma unroll
    for (int it = 0; it < NB; it++) {
        int c = it * 256 + tid;
        int col = c >> 4;
        int k8 = (c & 15) * 8;
        uint4 val = *(const uint4*)&Wt[col * 128 + k8];
        *(uint4*)&Bb[col * 128 + (k8 ^ ((col & 7) << 3))] = val;
    }
    __syncthreads();

    // ---- MFMA compute ----
    int w = tid >> 6, l = tid & 63;
    int g = l >> 4;
    int rA = l & 15;
    const int NT = F / 16;
    f32x4 acc[NT];
    #pragma unroll
    for (int ct = 0; ct < NT; ct++) {
        acc[ct][0] = 0.f; acc[ct][1] = 0.f; acc[ct][2] = 0.f; acc[ct][3] = 0.f;
    }
    int arow = w * 16 + rA;
    int abase = arow * 128;
    int sw = (rA & 7) << 3;   // arow&7 == rA&7; bcol&7 == rA&7
    #pragma unroll
    for (int ks = 0; ks < 4; ks++) {
        int koff = ks * 32 + g * 8;
        bf16x8 af = *(const bf16x8*)&Ab[abase + (koff ^ sw)];
        #pragma unroll
        for (int ct = 0; ct < NT; ct++) {
            int bcol = ct * 16 + rA;
            bf16x8 bfv = *(const bf16x8*)&Bb[bcol * 128 + (koff ^ sw)];
            acc[ct] = __builtin_amdgcn_mfma_f32_16x16x32_bf16(af, bfv, acc[ct], 0, 0, 0);
        }
    }

    // ---- epilogue: H (bf16) + fused dots ----
    float asv[NT], adv[NT];
    #pragma unroll
    for (int ct = 0; ct < NT; ct++) {
        asv[ct] = a_src[ct * 16 + rA];
        adv[ct] = a_dst[ct * 16 + rA];
    }
    float ps[4] = {0.f, 0.f, 0.f, 0.f};
    float pd[4] = {0.f, 0.f, 0.f, 0.f};
    #pragma unroll
    for (int ct = 0; ct < NT; ct++) {
        #pragma unroll
        for (int r = 0; r < 4; r++) {
            ps[r] += acc[ct][r] * asv[ct];
            pd[r] += acc[ct][r] * adv[ct];
        }
    }
    #pragma unroll
    for (int r = 0; r < 4; r++) {
        int grow = row0 + w * 16 + g * 4 + r;
        if (grow < NN) {
            #pragma unroll
            for (int ct = 0; ct < NT; ct++) {
                H[(size_t)grow * F + ct * 16 + rA] = f2b(acc[ct][r]);
            }
        }
    }
    #pragma unroll
    for (int r = 0; r < 4; r++) {
        #pragma unroll
        for (int off = 1; off < 16; off <<= 1) {
            ps[r] += __shfl_xor(ps[r], off);
            pd[r] += __shfl_xor(pd[r], off);
        }
    }
    if (rA == 0) {
        #pragma unroll
        for (int r = 0; r < 4; r++) {
            int grow = row0 + w * 16 + g * 4 + r;
            if (grow < NN) { sdot[grow] = ps[r]; ddot[grow] = pd[r]; }
        }
    }
}

// ---------------------------------------------------------------------------
// Shared helper: lane-parallel softmax weights into LDS.
// ---------------------------------------------------------------------------
__device__ __forceinline__ float stage_weights(const int* __restrict__ col_src,
                                               const float* __restrict__ s,
                                               float dn, int beg, int end, int lane,
                                               float* __restrict__ wl,
                                               int* __restrict__ wc) {
    float M = -INFINITY;
    for (int e0 = beg; e0 < end; e0 += 64) {
        int e = e0 + lane;
        float l = -INFINITY; int c = 0;
        if (e < end) { c = col_src[e]; l = leaky(s[c] + dn); }
        wl[e0 - beg + lane] = l;
        wc[e0 - beg + lane] = c;
        float cm = l;
        #pragma unroll
        for (int off = 32; off; off >>= 1) cm = fmaxf(cm, __shfl_xor(cm, off));
        M = fmaxf(M, cm);
    }
    float Sl = 0.f;
    for (int i0 = 0; i0 < end - beg; i0 += 64) {
        float u = __expf(wl[i0 + lane] - M);   // exp(-inf)=0 for pad
        wl[i0 + lane] = u;
        Sl += u;
    }
    #pragma unroll
    for (int off = 32; off; off >>= 1) Sl += __shfl_xor(Sl, off);
    return 1.f / (Sl + EPSF);
}

// ---------------------------------------------------------------------------
// Fused softmax+SpMM, layer 1 (F=128, ReLU, bf16 out). One wave per node.
// ---------------------------------------------------------------------------
__global__ __launch_bounds__(256) void k_fused1(const int* __restrict__ row_ptr,
                                                const int* __restrict__ col_src,
                                                const float* __restrict__ s,
                                                const float* __restrict__ d,
                                                const u16* __restrict__ H,
                                                const float* __restrict__ bias,
                                                u16* __restrict__ outb) {
    const int F = 128;
    __shared__ float wl[4][CAP];
    __shared__ int   wc[4][CAP];
    int wave = threadIdx.x >> 6;
    int lane = threadIdx.x & 63;
    int n = blockIdx.x * 4 + wave;
    if (n >= NN) return;
    int beg = row_ptr[n], end = row_ptr[n + 1];
    int deg = end - beg;
    float dn = d[n];
    float2 acc = {0.f, 0.f};
    float invS;

    if (deg <= CAP) {
        invS = stage_weights(col_src, s, dn, beg, end, lane, wl[wave], wc[wave]);
        int i = 0;
        for (; i + 4 <= deg; i += 4) {
            float u0 = wl[wave][i], u1 = wl[wave][i + 1];
            float u2 = wl[wave][i + 2], u3 = wl[wave][i + 3];
            int c0 = wc[wave][i], c1 = wc[wave][i + 1];
            int c2 = wc[wave][i + 2], c3 = wc[wave][i + 3];
            ushort2 r0 = *(const ushort2*)&H[(size_t)c0 * F + lane * 2];
            ushort2 r1 = *(const ushort2*)&H[(size_t)c1 * F + lane * 2];
            ushort2 r2 = *(const ushort2*)&H[(size_t)c2 * F + lane * 2];
            ushort2 r3 = *(const ushort2*)&H[(size_t)c3 * F + lane * 2];
            acc.x += u0 * b2f(r0.x); acc.y += u0 * b2f(r0.y);
            acc.x += u1 * b2f(r1.x); acc.y += u1 * b2f(r1.y);
            acc.x += u2 * b2f(r2.x); acc.y += u2 * b2f(r2.y);
            acc.x += u3 * b2f(r3.x); acc.y += u3 * b2f(r3.y);
        }
        for (; i < deg; ++i) {
            float u = wl[wave][i];
            int c = wc[wave][i];
            ushort2 r = *(const ushort2*)&H[(size_t)c * F + lane * 2];
            acc.x += u * b2f(r.x); acc.y += u * b2f(r.y);
        }
    } else {  // fallback: online softmax + recompute
        float M = -INFINITY, S = 0.f;
        for (int e0 = beg; e0 < end; e0 += 64) {
            int e = e0 + lane;
            float l = (e < end) ? leaky(s[col_src[e]] + dn) : -INFINITY;
            float cm = l;
            #pragma unroll
            for (int off = 32; off; off >>= 1) cm = fmaxf(cm, __shfl_xor(cm, off));
            float Mn = fmaxf(M, cm);
            float p = (e < end) ? __expf(l - Mn) : 0.f;
            #pragma unroll
            for (int off = 32; off; off >>= 1) p += __shfl_xor(p, off);
            S = S * __expf(M - Mn) + p;
            M = Mn;
        }
        invS = 1.f / (S + EPSF);
        for (int e = beg; e < end; ++e) {
            int c = col_src[e];
            float u = __expf(leaky(s[c] + dn) - M);
            ushort2 r = *(const ushort2*)&H[(size_t)c * F + lane * 2];
            acc.x += u * b2f(r.x); acc.y += u * b2f(r.y);
        }
    }
    float2 b = *(const float2*)&bias[lane * 2];
    acc.x = fmaxf(acc.x * invS + b.x, 0.f);
    acc.y = fmaxf(acc.y * invS + b.y, 0.f);
    ushort2 o; o.x = f2b(acc.x); o.y = f2b(acc.y);
    *(ushort2*)&outb[(size_t)n * F + lane * 2] = o;
}

// ---------------------------------------------------------------------------
// Fused softmax+SpMM+mean-pool accumulate, layer 2 (F=64).
// ---------------------------------------------------------------------------
#define NPW 8
__global__ __launch_bounds__(256) void k_fused2(const int* __restrict__ row_ptr,
                                                const int* __restrict__ col_src,
                                                const float* __restrict__ s,
                                                const float* __restrict__ d,
                                                const u16* __restrict__ H,
                                                const float* __restrict__ bias,
                                                const int* __restrict__ batch,
                                                float* __restrict__ sums) {
    const int F = 64;
    __shared__ float wl[4][CAP];
    __shared__ int   wc[4][CAP];
    int wave = threadIdx.x >> 6;
    int lane = threadIdx.x & 63;
    int base = (blockIdx.x * 4 + wave) * NPW;
    if (base >= NN) return;
    int lim = base + NPW; if (lim > NN) lim = NN;
    float bs = bias[lane];
    float gacc = 0.f;
    int gb = batch[base];

    for (int n = base; n < lim; ++n) {
        int b = batch[n];
        if (b != gb) {
            atomicAdd(&sums[gb * COUT + lane], gacc);
            gacc = 0.f; gb = b;
        }
        int beg = row_ptr[n], end = row_ptr[n + 1];
        int deg = end - beg;
        float dn = d[n];
        float acc = 0.f;
        float invS;

        if (deg <= CAP) {
            invS = stage_weights(col_src, s, dn, beg, end, lane, wl[wave], wc[wave]);
            int i = 0;
            for (; i + 4 <= deg; i += 4) {
                float u0 = wl[wave][i], u1 = wl[wave][i + 1];
                float u2 = wl[wave][i + 2], u3 = wl[wave][i + 3];
                int c0 = wc[wave][i], c1 = wc[wave][i + 1];
                int c2 = wc[wave][i + 2], c3 = wc[wave][i + 3];
                u16 r0 = H[(size_t)c0 * F + lane];
                u16 r1 = H[(size_t)c1 * F + lane];
                u16 r2 = H[(size_t)c2 * F + lane];
                u16 r3 = H[(size_t)c3 * F + lane];
                acc += u0 * b2f(r0) + u1 * b2f(r1) + u2 * b2f(r2) + u3 * b2f(r3);
            }
            for (; i < deg; ++i) {
                acc += wl[wave][i] * b2f(H[(size_t)wc[wave][i] * F + lane]);
            }
        } else {  // fallback
            float M = -INFINITY, S = 0.f;
            for (int e0 = beg; e0 < end; e0 += 64) {
                int e = e0 + lane;
                float l = (e < end) ? leaky(s[col_src[e]] + dn) : -INFINITY;
                float cm = l;
                #pragma unroll
                for (int off = 32; off; off >>= 1) cm = fmaxf(cm, __shfl_xor(cm, off));
                float Mn = fmaxf(M, cm);
                float p = (e < end) ? __expf(l - Mn) : 0.f;
                #pragma unroll
                for (int off = 32; off; off >>= 1) p += __shfl_xor(p, off);
                S = S * __expf(M - Mn) + p;
                M = Mn;
            }
            invS = 1.f / (S + EPSF);
            for (int e = beg; e < end; ++e) {
                int c = col_src[e];
                acc += __expf(leaky(s[c] + dn) - M) * b2f(H[(size_t)c * F + lane]);
            }
        }
        gacc += acc * invS + bs;
    }
    atomicAdd(&sums[gb * COUT + lane], gacc);
}

// ---------------------------------------------------------------------------
// mean + log_softmax; one wave per graph
// ---------------------------------------------------------------------------
__global__ __launch_bounds__(256) void k_logsm(const float* __restrict__ sums,
                                               const int* __restrict__ batch,
                                               float* __restrict__ out) {
    int wave = threadIdx.x >> 6;
    int lane = threadIdx.x & 63;
    int g = blockIdx.x * 4 + wave;
    if (g >= BB) return;
    int lo = 0, hi = NN;
    while (lo < hi) { int mid = (lo + hi) >> 1; if (batch[mid] < g) lo = mid + 1; else hi = mid; }
    int l2 = lo, h2 = NN;
    while (l2 < h2) { int mid = (l2 + h2) >> 1; if (batch[mid] < g + 1) l2 = mid + 1; else h2 = mid; }
    float cnt = (float)(h2 - lo);
    float mean = sums[g * COUT + lane] / fmaxf(cnt, 1.f);
    float mx = mean;
    #pragma unroll
    for (int off = 32; off; off >>= 1) mx = fmaxf(mx, __shfl_xor(mx, off));
    float ex = __expf(mean - mx);
    float sm = ex;
    #pragma unroll
    for (int off = 32; off; off >>= 1) sm += __shfl_xor(sm, off);
    out[g * COUT + lane] = mean - mx - logf(sm);
}

// ---------------------------------------------------------------------------
extern "C" void kernel_launch(void* const* d_in, const int* in_sizes, int n_in,
                              void* d_out, int out_size, void* d_ws, size_t ws_size,
                              hipStream_t stream) {
    const float* x      = (const float*)d_in[0];
    const int*   eidx   = (const int*)d_in[1];
    const int*   batch  = (const int*)d_in[2];
    const float* W1     = (const float*)d_in[3];
    const float* a_src1 = (const float*)d_in[4];
    const float* a_dst1 = (const float*)d_in[5];
    const float* b1     = (const float*)d_in[6];
    const float* W2     = (const float*)d_in[7];
    const float* a_src2 = (const float*)d_in[8];
    const float* a_dst2 = (const float*)d_in[9];
    const float* b2     = (const float*)d_in[10];
    float* out = (float*)d_out;

    const int* src = eidx;        // edge_index[0]
    const int* dst = eidx + EE;   // edge_index[1]

    char* w = (char*)d_ws;
    auto alloc = [&](size_t bytes) { void* p = (void*)w; w += (bytes + 255) & ~(size_t)255; return p; };
    float* sums  = (float*)alloc((size_t)BB * COUT * 4);
    float* s1    = (float*)alloc((size_t)NN * 4);
    float* d1    = (float*)alloc((size_t)NN * 4);
    float* s2    = (float*)alloc((size_t)NN * 4);
    float* d2    = (float*)alloc((size_t)NN * 4);
    int* row_ptr = (int*)alloc((size_t)(NN + 1) * 4);
    int* cursor  = (int*)alloc((size_t)NN * 4);
    int* count   = (int*)alloc((size_t)NN * 4);
    int* tmp     = (int*)alloc((size_t)NN * 4);
    int* partial = (int*)alloc((size_t)64 * 4);
    int* col_src = (int*)alloc((size_t)EP * 4);
    u16* h1      = (u16*)alloc((size_t)NN * 128 * 2);
    u16* x2      = (u16*)alloc((size_t)NN * 128 * 2);
    u16* h2      = (u16*)alloc((size_t)NN * 64 * 2);
    u16* W1t     = (u16*)alloc((size_t)128 * 128 * 2);
    u16* W2t     = (u16*)alloc((size_t)64 * 128 * 2);

    dim3 blk(256);
    int gN  = (NN + 255) / 256;
    int gE  = (EE + 255) / 256;
    int gN4 = (NN + 3) / 4;
    int gScan = (NN + 1023) / 1024;          // 49
    int gM  = (NN + 63) / 64;                // 782

    // prep + CSR build
    k_prep<<<96, blk, 0, stream>>>(W1, W2, W1t, W2t);
    k_init<<<gN, blk, 0, stream>>>(count, sums);
    k_count_edges<<<gE, blk, 0, stream>>>(dst, count);
    k_scan1<<<gScan, 1024, 0, stream>>>(count, tmp, partial);
    k_scan2<<<gScan, 1024, 0, stream>>>(tmp, partial, row_ptr, cursor);
    k_scatter<<<2048, blk, 0, stream>>>(src, dst, cursor, col_src);

    // Layer 1
    k_gemm_mfma<128, false><<<gM, blk, 0, stream>>>(x, W1t, h1, a_src1, a_dst1, s1, d1);
    k_fused1<<<gN4, blk, 0, stream>>>(row_ptr, col_src, s1, d1, h1, b1, x2);

    // Layer 2
    k_gemm_mfma<64, true><<<gM, blk, 0, stream>>>(x2, W2t, h2, a_src2, a_dst2, s2, d2);
    int gP = (NN + 4 * NPW - 1) / (4 * NPW);
    k_fused2<<<gP, blk, 0, stream>>>(row_ptr, col_src, s2, d2, h2, b2, batch, sums);

    // mean + log_softmax
    k_logsm<<<(BB + 3) / 4, blk, 0, stream>>>(sums, batch, out);
}